// Round 9
// baseline (41.320 us; speedup 1.0000x reference)
//
#include <hip/hip_runtime.h>

// YOLOv3 dense decode, 3 scales. Inputs (f32):
//  d_in[0] output_13 [32,255,13,13], d_in[1] output_26 [32,255,26,26],
//  d_in[2] output_52 [32,255,52,52], d_in[3..5] anchors [3,2] each,
//  d_in[6] thresh scalar.
// Output (f32 flat): boxes [340704,6] then valid [340704] (0.0/1.0).
//
// Round 9 = Round-2 float4 kernel (best, 28.9us) with ONE change:
// all output stores are non-temporal. (Round 8 failed to compile:
// __builtin_nontemporal_store needs a clang ext_vector type, not HIP float2.)
// Theory: steady-state FETCH_SIZE=62MB despite 116MB input < 256MB L3 —
// output writes evict input from L2/L3 between graph replays. NT stores
// (evict-first, no-allocate) keep the input resident -> reads become L3 hits.

typedef float v2f __attribute__((ext_vector_type(2)));

constexpr int NCLS  = 80;
constexpr int BATCH = 32;
constexpr int HW13  = 169;
constexpr int HW26  = 676;
constexpr int HW52  = 2704;
constexpr int N13   = BATCH * 3 * HW13;   // 16224
constexpr int N26   = BATCH * 3 * HW26;   // 64896
constexpr int N52   = BATCH * 3 * HW52;   // 259584
constexpr int NTOT  = N13 + N26 + N52;    // 340704
constexpr int R13   = 0;
constexpr int R26   = N13;
constexpr int R52   = N13 + N26;

constexpr int OUT13 = (HW13 + 63) / 64;        // 3  (scalar path, per-hw)
constexpr int OUT26 = (HW26 / 4 + 63) / 64;    // 3  (float4 path, per 4-hw chunk)
constexpr int OUT52 = (HW52 / 4 + 63) / 64;    // 11
constexpr int B13   = BATCH * OUT13;           // 96
constexpr int B26   = BATCH * OUT26;           // 96
constexpr int B52   = BATCH * OUT52;           // 352
constexpr int NBLK  = B13 + B26 + B52;         // 544

__device__ __forceinline__ float sigm(float x) { return 1.0f / (1.0f + expf(-x)); }

__device__ __forceinline__ void store_row_nt(float* __restrict__ boxes,
                                             float* __restrict__ valid,
                                             int row, float conf, float x1,
                                             float y1, float x2, float y2,
                                             float cls, float th)
{
    v2f* o = reinterpret_cast<v2f*>(boxes + (size_t)row * 6);  // 24B-aligned (8B ok)
    v2f w0; w0.x = conf; w0.y = x1;
    v2f w1; w1.x = y1;   w1.y = x2;
    v2f w2; w2.x = y2;   w2.y = cls;
    __builtin_nontemporal_store(w0, o + 0);
    __builtin_nontemporal_store(w1, o + 1);
    __builtin_nontemporal_store(w2, o + 2);
    __builtin_nontemporal_store(conf > th ? 1.0f : 0.0f, valid + row);
}

// ---------- scalar path (scale 13: HW odd, float4 misaligned) ----------
template <int HW, int W>
__device__ __forceinline__ void decode_scalar(
    const float* __restrict__ in, const float* __restrict__ anc,
    float t, int b, int a, int hw, int rowofs, float th,
    float* __restrict__ boxes, float* __restrict__ valid)
{
    const int x = hw % W;
    const int y = hw / W;
    const float* p = in + (size_t)(b * 255 + a * 85) * HW + hw;

    const float t0 = p[0];
    const float t1 = p[(size_t)1 * HW];
    const float t2 = p[(size_t)2 * HW];
    const float t3 = p[(size_t)3 * HW];
    const float t4 = p[(size_t)4 * HW];

    float best = p[(size_t)5 * HW];
    int cls = 0;
#pragma unroll
    for (int k = 1; k < NCLS; ++k) {
        const float v = p[(size_t)(5 + k) * HW];
        cls  = v > best ? k : cls;
        best = fmaxf(v, best);
    }

    const float aw = anc[a * 2 + 0], ah = anc[a * 2 + 1];
    const float conf = sigm(t0);
    const float cx   = ((float)x + sigm(t1)) * t;
    const float cy   = ((float)y + sigm(t2)) * t;
    const float w    = aw * expf(t3);
    const float h    = ah * expf(t4);
    const float x1   = cx - w * 0.5f;
    const float y1   = cy - h * 0.5f;

    const int row = rowofs + (b * HW + hw) * 3 + a;
    store_row_nt(boxes, valid, row, conf, x1, y1, x1 + w, y1 + h, (float)cls, th);
}

// ---------- float4 path (scales 26/52: HW % 4 == 0, rows 16B-aligned) ----------
template <int HW, int W>
__device__ __forceinline__ void decode_vec4(
    const float* __restrict__ in, const float* __restrict__ anc,
    float t, int b, int a, int c, int rowofs, float th,
    float* __restrict__ boxes, float* __restrict__ valid)
{
    constexpr int HWc = HW / 4;
    const float4* __restrict__ p =
        reinterpret_cast<const float4*>(in + (size_t)(b * 255 + a * 85) * HW) + c;

    const float4 t0 = p[0];
    const float4 t1 = p[(size_t)1 * HWc];
    const float4 t2 = p[(size_t)2 * HWc];
    const float4 t3 = p[(size_t)3 * HWc];
    const float4 t4 = p[(size_t)4 * HWc];

    float4 bv = p[(size_t)5 * HWc];
    float b0 = bv.x, b1 = bv.y, b2 = bv.z, b3 = bv.w;
    int c0 = 0, c1 = 0, c2 = 0, c3 = 0;
#pragma unroll
    for (int k = 1; k < NCLS; ++k) {
        const float4 v = p[(size_t)(5 + k) * HWc];
        c0 = v.x > b0 ? k : c0;  b0 = fmaxf(v.x, b0);
        c1 = v.y > b1 ? k : c1;  b1 = fmaxf(v.y, b1);
        c2 = v.z > b2 ? k : c2;  b2 = fmaxf(v.z, b2);
        c3 = v.w > b3 ? k : c3;  b3 = fmaxf(v.w, b3);
    }

    const float aw = anc[a * 2 + 0], ah = anc[a * 2 + 1];

#define EMIT(j, s0, s1, s2, s3, s4, cc)                                   \
    {                                                                     \
        const int hw = 4 * c + (j);                                       \
        const int x = hw % W;                                             \
        const int y = hw / W;                                             \
        const float conf = sigm(s0);                                      \
        const float cx = ((float)x + sigm(s1)) * t;                       \
        const float cy = ((float)y + sigm(s2)) * t;                       \
        const float w_ = aw * expf(s3);                                   \
        const float h_ = ah * expf(s4);                                   \
        const float x1 = cx - w_ * 0.5f;                                  \
        const float y1 = cy - h_ * 0.5f;                                  \
        const int row = rowofs + (b * HW + hw) * 3 + a;                   \
        store_row_nt(boxes, valid, row, conf, x1, y1, x1 + w_, y1 + h_,   \
                     (float)(cc), th);                                    \
    }

    EMIT(0, t0.x, t1.x, t2.x, t3.x, t4.x, c0);
    EMIT(1, t0.y, t1.y, t2.y, t3.y, t4.y, c1);
    EMIT(2, t0.z, t1.z, t2.z, t3.z, t4.z, c2);
    EMIT(3, t0.w, t1.w, t2.w, t3.w, t4.w, c3);
#undef EMIT
}

__global__ __launch_bounds__(192) void yolo_decode_kernel(
    const float* __restrict__ in13, const float* __restrict__ in26,
    const float* __restrict__ in52,
    const float* __restrict__ a13, const float* __restrict__ a26,
    const float* __restrict__ a52,
    const float* __restrict__ pth, float* __restrict__ out)
{
    const int a    = threadIdx.x >> 6;   // wave index = anchor (wave-uniform)
    const int lane = threadIdx.x & 63;
    const float th = *pth;
    float* boxes = out;
    float* valid = out + (size_t)NTOT * 6;

    int blk = blockIdx.x;
    if (blk < B13) {
        const int b  = blk / OUT13;
        const int co = blk % OUT13;
        const int hw = co * 64 + lane;
        if (hw >= HW13) return;
        decode_scalar<HW13, 13>(in13, a13, 32.0f, b, a, hw, R13, th, boxes, valid);
    } else if (blk < B13 + B26) {
        blk -= B13;
        const int b  = blk / OUT26;
        const int co = blk % OUT26;
        const int c  = co * 64 + lane;
        if (c >= HW26 / 4) return;
        decode_vec4<HW26, 26>(in26, a26, 16.0f, b, a, c, R26, th, boxes, valid);
    } else {
        blk -= (B13 + B26);
        const int b  = blk / OUT52;
        const int co = blk % OUT52;
        const int c  = co * 64 + lane;
        if (c >= HW52 / 4) return;
        decode_vec4<HW52, 52>(in52, a52, 8.0f, b, a, c, R52, th, boxes, valid);
    }
}

extern "C" void kernel_launch(void* const* d_in, const int* in_sizes, int n_in,
                              void* d_out, int out_size, void* d_ws, size_t ws_size,
                              hipStream_t stream) {
    const float* in13 = (const float*)d_in[0];
    const float* in26 = (const float*)d_in[1];
    const float* in52 = (const float*)d_in[2];
    const float* a13  = (const float*)d_in[3];
    const float* a26  = (const float*)d_in[4];
    const float* a52  = (const float*)d_in[5];
    const float* pth  = (const float*)d_in[6];
    float* out = (float*)d_out;

    yolo_decode_kernel<<<NBLK, 192, 0, stream>>>(in13, in26, in52,
                                                 a13, a26, a52, pth, out);
}

// Round 10
// 40.370 us; speedup vs baseline: 1.0235x; 1.0235x over previous
//
#include <hip/hip_runtime.h>

// YOLOv3 dense decode, 3 scales. Inputs (f32):
//  d_in[0] output_13 [32,255,13,13], d_in[1] output_26 [32,255,26,26],
//  d_in[2] output_52 [32,255,52,52], d_in[3..5] anchors [3,2] each,
//  d_in[6] thresh scalar.
// Output (f32 flat): boxes [340704,6] then valid [340704] (0.0/1.0).
//
// Round 10: R2 float4 kernel re-partitioned into 1-wave (64-thread) blocks.
//  - Same per-wave work as R2 (64 float4-chunks of one (b,a) slab), but 1632
//    independently schedulable blocks -> ~12 waves/CU resident -> in-flight
//    bytes/CU ~60KB >> 20KB needed to hide latency at 6.3 TB/s.
//  - Anchor-sibling blocks (same b,chunk; a=0,1,2) get ids differing by 8:
//    id%8 XCD round-robin puts them on the same XCD L2 -> partial-line
//    stores (24B/72B) merge into full lines before HBM.
//  - Plain stores (Round 9 showed NT stores cause 4x write amplification).

constexpr int NCLS  = 80;
constexpr int BATCH = 32;
constexpr int HW13  = 169;
constexpr int HW26  = 676;
constexpr int HW52  = 2704;
constexpr int N13   = BATCH * 3 * HW13;   // 16224
constexpr int N26   = BATCH * 3 * HW26;   // 64896
constexpr int N52   = BATCH * 3 * HW52;   // 259584
constexpr int NTOT  = N13 + N26 + N52;    // 340704
constexpr int R13   = 0;
constexpr int R26   = N13;
constexpr int R52   = N13 + N26;

// per-(b,a) chunk counts (256 hw per wave; float4 path uses 64 float4-chunks)
constexpr int CO52 = 11;                       // ceil(2704/256)
constexpr int CO26 = 3;                        // ceil(676/256)
constexpr int CO13 = 3;                        // ceil(169/64) (scalar path)
constexpr int S52  = BATCH * CO52;             // 352 sibling groups (=44*8)
constexpr int S26  = BATCH * CO26;             // 96  (=12*8)
constexpr int S13  = BATCH * CO13;             // 96  (=12*8)
constexpr int NB52 = S52 * 3;                  // 1056
constexpr int NB26 = S26 * 3;                  // 288
constexpr int NB13 = S13 * 3;                  // 288
constexpr int NBLK = NB52 + NB26 + NB13;       // 1632

__device__ __forceinline__ float sigm(float x) { return 1.0f / (1.0f + expf(-x)); }

// ---------- scalar path (scale 13: HW odd, float4 misaligned) ----------
template <int HW, int W>
__device__ __forceinline__ void decode_scalar(
    const float* __restrict__ in, const float* __restrict__ anc,
    float t, int b, int a, int hw, int rowofs, float th,
    float* __restrict__ boxes, float* __restrict__ valid)
{
    const int x = hw % W;
    const int y = hw / W;
    const float* p = in + (size_t)(b * 255 + a * 85) * HW + hw;

    const float t0 = p[0];
    const float t1 = p[(size_t)1 * HW];
    const float t2 = p[(size_t)2 * HW];
    const float t3 = p[(size_t)3 * HW];
    const float t4 = p[(size_t)4 * HW];

    float best = p[(size_t)5 * HW];
    int cls = 0;
#pragma unroll
    for (int k = 1; k < NCLS; ++k) {
        const float v = p[(size_t)(5 + k) * HW];
        cls  = v > best ? k : cls;
        best = fmaxf(v, best);
    }

    const float aw = anc[a * 2 + 0], ah = anc[a * 2 + 1];
    const float conf = sigm(t0);
    const float cx   = ((float)x + sigm(t1)) * t;
    const float cy   = ((float)y + sigm(t2)) * t;
    const float w    = aw * expf(t3);
    const float h    = ah * expf(t4);
    const float x1   = cx - w * 0.5f;
    const float y1   = cy - h * 0.5f;

    const int row = rowofs + (b * HW + hw) * 3 + a;
    float* o = boxes + (size_t)row * 6;
    o[0] = conf; o[1] = x1; o[2] = y1; o[3] = x1 + w; o[4] = y1 + h; o[5] = (float)cls;
    valid[row] = conf > th ? 1.0f : 0.0f;
}

// ---------- float4 path (scales 26/52: HW % 4 == 0, rows 16B-aligned) ----------
template <int HW, int W>
__device__ __forceinline__ void decode_vec4(
    const float* __restrict__ in, const float* __restrict__ anc,
    float t, int b, int a, int c, int rowofs, float th,
    float* __restrict__ boxes, float* __restrict__ valid)
{
    constexpr int HWc = HW / 4;
    const float4* __restrict__ p =
        reinterpret_cast<const float4*>(in + (size_t)(b * 255 + a * 85) * HW) + c;

    const float4 t0 = p[0];
    const float4 t1 = p[(size_t)1 * HWc];
    const float4 t2 = p[(size_t)2 * HWc];
    const float4 t3 = p[(size_t)3 * HWc];
    const float4 t4 = p[(size_t)4 * HWc];

    float4 bv = p[(size_t)5 * HWc];
    float b0 = bv.x, b1 = bv.y, b2 = bv.z, b3 = bv.w;
    int c0 = 0, c1 = 0, c2 = 0, c3 = 0;
#pragma unroll
    for (int k = 1; k < NCLS; ++k) {
        const float4 v = p[(size_t)(5 + k) * HWc];
        c0 = v.x > b0 ? k : c0;  b0 = fmaxf(v.x, b0);
        c1 = v.y > b1 ? k : c1;  b1 = fmaxf(v.y, b1);
        c2 = v.z > b2 ? k : c2;  b2 = fmaxf(v.z, b2);
        c3 = v.w > b3 ? k : c3;  b3 = fmaxf(v.w, b3);
    }

    const float aw = anc[a * 2 + 0], ah = anc[a * 2 + 1];

#define EMIT(j, s0, s1, s2, s3, s4, cc)                                   \
    {                                                                     \
        const int hw = 4 * c + (j);                                       \
        const int x = hw % W;                                             \
        const int y = hw / W;                                             \
        const float conf = sigm(s0);                                      \
        const float cx = ((float)x + sigm(s1)) * t;                       \
        const float cy = ((float)y + sigm(s2)) * t;                       \
        const float w_ = aw * expf(s3);                                   \
        const float h_ = ah * expf(s4);                                   \
        const float x1 = cx - w_ * 0.5f;                                  \
        const float y1 = cy - h_ * 0.5f;                                  \
        const int row = rowofs + (b * HW + hw) * 3 + a;                   \
        float* o = boxes + (size_t)row * 6;                               \
        o[0] = conf; o[1] = x1; o[2] = y1;                                \
        o[3] = x1 + w_; o[4] = y1 + h_; o[5] = (float)(cc);               \
        valid[row] = conf > th ? 1.0f : 0.0f;                             \
    }

    EMIT(0, t0.x, t1.x, t2.x, t3.x, t4.x, c0);
    EMIT(1, t0.y, t1.y, t2.y, t3.y, t4.y, c1);
    EMIT(2, t0.z, t1.z, t2.z, t3.z, t4.z, c2);
    EMIT(3, t0.w, t1.w, t2.w, t3.w, t4.w, c3);
#undef EMIT
}

// sibling-group id decode: within a scale, blocks are laid out as
// id = g*24 + a*8 + r  with sibling group s = g*8 + r.  The three anchor
// siblings of a group differ by 8 in id -> same id%8 -> same XCD.
__device__ __forceinline__ void sib_decode(int id, int& a, int& s)
{
    const int g   = id / 24;
    const int rem = id % 24;
    a = rem >> 3;
    s = g * 8 + (rem & 7);
}

__global__ __launch_bounds__(64, 3) void yolo_decode_kernel(
    const float* __restrict__ in13, const float* __restrict__ in26,
    const float* __restrict__ in52,
    const float* __restrict__ a13, const float* __restrict__ a26,
    const float* __restrict__ a52,
    const float* __restrict__ pth, float* __restrict__ out)
{
    const int lane = threadIdx.x;
    const float th = *pth;
    float* boxes = out;
    float* valid = out + (size_t)NTOT * 6;

    int id = blockIdx.x;
    if (id < NB52) {
        int a, s;  sib_decode(id, a, s);
        const int b  = s / CO52;
        const int co = s % CO52;
        const int c  = co * 64 + lane;
        if (c >= HW52 / 4) return;
        decode_vec4<HW52, 52>(in52, a52, 8.0f, b, a, c, R52, th, boxes, valid);
    } else if (id < NB52 + NB26) {
        int a, s;  sib_decode(id - NB52, a, s);
        const int b  = s / CO26;
        const int co = s % CO26;
        const int c  = co * 64 + lane;
        if (c >= HW26 / 4) return;
        decode_vec4<HW26, 26>(in26, a26, 16.0f, b, a, c, R26, th, boxes, valid);
    } else {
        int a, s;  sib_decode(id - NB52 - NB26, a, s);
        const int b  = s / CO13;
        const int co = s % CO13;
        const int hw = co * 64 + lane;
        if (hw >= HW13) return;
        decode_scalar<HW13, 13>(in13, a13, 32.0f, b, a, hw, R13, th, boxes, valid);
    }
}

extern "C" void kernel_launch(void* const* d_in, const int* in_sizes, int n_in,
                              void* d_out, int out_size, void* d_ws, size_t ws_size,
                              hipStream_t stream) {
    const float* in13 = (const float*)d_in[0];
    const float* in26 = (const float*)d_in[1];
    const float* in52 = (const float*)d_in[2];
    const float* a13  = (const float*)d_in[3];
    const float* a26  = (const float*)d_in[4];
    const float* a52  = (const float*)d_in[5];
    const float* pth  = (const float*)d_in[6];
    float* out = (float*)d_out;

    yolo_decode_kernel<<<NBLK, 64, 0, stream>>>(in13, in26, in52,
                                                a13, a26, a52, pth, out);
}